// Round 5
// baseline (198.389 us; speedup 1.0000x reference)
//
#include <hip/hip_runtime.h>
#include <hip/hip_cooperative_groups.h>

namespace cg = cooperative_groups;

#define D 128
#define LDW 136   // padded LDS row (bf16 elems): +8 → 2-way bank aliasing (free)

typedef __attribute__((ext_vector_type(8))) short bf16x8;
typedef __attribute__((ext_vector_type(4))) float f32x4;

static __device__ __forceinline__ ushort f2bf(float f) {
    union { float f; unsigned u; } c; c.f = f;
    unsigned u = c.u;
    return (ushort)((u + 0x7fffu + ((u >> 16) & 1u)) >> 16);  // RNE
}
static __device__ __forceinline__ float bflo(unsigned v) {
    union { unsigned u; float f; } c; c.u = v << 16; return c.f;
}
static __device__ __forceinline__ float bfhi(unsigned v) {
    union { unsigned u; float f; } c; c.u = v & 0xffff0000u; return c.f;
}

// ---------------- prep: deg = 0, xb = bf16(x), Wb = bf16(W) ----------------
__global__ __launch_bounds__(256) void gin_prep(const float* __restrict__ x,
                                                ushort* __restrict__ xb, int n4,
                                                const float* __restrict__ W,
                                                ushort* __restrict__ Wb, int w4,
                                                int* __restrict__ deg, int ndeg4) {
    int stride = gridDim.x * 256;
    int tid0 = blockIdx.x * 256 + threadIdx.x;
    for (int i = tid0; i < ndeg4; i += stride)
        ((int4*)deg)[i] = make_int4(0, 0, 0, 0);
    for (int i = tid0; i < n4; i += stride) {
        float4 v = ((const float4*)x)[i];
        ushort4 o;
        o.x = f2bf(v.x); o.y = f2bf(v.y); o.z = f2bf(v.z); o.w = f2bf(v.w);
        ((ushort4*)xb)[i] = o;
    }
    for (int i = tid0; i < w4; i += stride) {
        float4 v = ((const float4*)W)[i];
        ushort4 o;
        o.x = f2bf(v.x); o.y = f2bf(v.y); o.z = f2bf(v.z); o.w = f2bf(v.w);
        ((ushort4*)Wb)[i] = o;
    }
}

// ---------------- cooperative CSR build: hist + scan + fill in one kernel ----------------
// grid = nb blocks (nb = ceil(nnodes/256) <= 256), 256 threads
__global__ __launch_bounds__(256) void gin_csr(const int* __restrict__ src,
                                               const int* __restrict__ dst,
                                               int* __restrict__ deg,
                                               int* __restrict__ bsum,
                                               int* __restrict__ rowptr,
                                               int* __restrict__ cursor,
                                               int* __restrict__ csr_src,
                                               int nnodes, int nedges) {
    cg::grid_group grid = cg::this_grid();
    __shared__ int sh[256];

    int tid = threadIdx.x;
    int bid = blockIdx.x;
    int nthreads = gridDim.x * 256;
    int gtid = bid * 256 + tid;

    // A: histogram
    for (int e = gtid; e < nedges; e += nthreads)
        atomicAdd(&deg[dst[e]], 1);
    grid.sync();

    // B: per-block sum of deg chunk
    int i = gtid;
    int dv = (i < nnodes) ? deg[i] : 0;
    sh[tid] = dv;
    __syncthreads();
    for (int off = 128; off > 0; off >>= 1) {
        if (tid < off) sh[tid] += sh[tid + off];
        __syncthreads();
    }
    if (tid == 0) bsum[bid] = sh[0];
    grid.sync();

    // C1: block offset = sum bsum[0..bid) (each block computes its own, redundantly)
    int bv = (tid < bid) ? bsum[tid] : 0;   // tid<bid<=nb-1 ==> in range
    sh[tid] = bv;
    __syncthreads();
    for (int off = 128; off > 0; off >>= 1) {
        if (tid < off) sh[tid] += sh[tid + off];
        __syncthreads();
    }
    int boffset = sh[0];
    __syncthreads();

    // C2: block-local inclusive scan of dv, then exclusive + offset
    sh[tid] = dv;
    __syncthreads();
    for (int off = 1; off < 256; off <<= 1) {
        int t = (tid >= off) ? sh[tid - off] : 0;
        __syncthreads();
        sh[tid] += t;
        __syncthreads();
    }
    int ex = boffset + sh[tid] - dv;
    if (i < nnodes) {
        rowptr[i] = ex;
        cursor[i] = ex;
    }
    if (gtid == 0) rowptr[nnodes] = nedges;  // total degree == edge count
    grid.sync();

    // D: fill buckets
    for (int e = gtid; e < nedges; e += nthreads) {
        int pos = atomicAdd(&cursor[dst[e]], 1);
        csr_src[pos] = src[e];
    }
}

// ---------------- non-coop fallback CSR kernels (used only if coop launch fails) ----------------
__global__ __launch_bounds__(256) void gin_hist(const int* __restrict__ dst,
                                                int* __restrict__ deg, int nedges) {
    int e = blockIdx.x * 256 + threadIdx.x;
    if (e < nedges) atomicAdd(&deg[dst[e]], 1);
}
__global__ __launch_bounds__(256) void gin_bsum(const int* __restrict__ deg,
                                                int* __restrict__ bsum, int n) {
    __shared__ int sh[256];
    int i = blockIdx.x * 256 + threadIdx.x;
    int v = (i < n) ? deg[i] : 0;
    sh[threadIdx.x] = v;
    __syncthreads();
    for (int off = 128; off > 0; off >>= 1) {
        if (threadIdx.x < off) sh[threadIdx.x] += sh[threadIdx.x + off];
        __syncthreads();
    }
    if (threadIdx.x == 0) bsum[blockIdx.x] = sh[0];
}
__global__ __launch_bounds__(256) void gin_bscan(const int* __restrict__ bsum,
                                                 int* __restrict__ boff,
                                                 int* __restrict__ rowptr,
                                                 int nb, int n) {
    __shared__ int sh[256];
    int i = threadIdx.x;
    int v = (i < nb) ? bsum[i] : 0;
    sh[i] = v;
    __syncthreads();
    for (int off = 1; off < 256; off <<= 1) {
        int t = (i >= off) ? sh[i - off] : 0;
        __syncthreads();
        sh[i] += t;
        __syncthreads();
    }
    if (i < nb) boff[i] = sh[i] - v;
    if (i == 255) rowptr[n] = sh[255];
}
__global__ __launch_bounds__(256) void gin_scan(const int* __restrict__ deg,
                                                const int* __restrict__ boff,
                                                int* __restrict__ rowptr,
                                                int* __restrict__ cursor, int n) {
    __shared__ int sh[256];
    int i = blockIdx.x * 256 + threadIdx.x;
    int v = (i < n) ? deg[i] : 0;
    sh[threadIdx.x] = v;
    __syncthreads();
    for (int off = 1; off < 256; off <<= 1) {
        int t = (threadIdx.x >= off) ? sh[threadIdx.x - off] : 0;
        __syncthreads();
        sh[threadIdx.x] += t;
        __syncthreads();
    }
    if (i < n) {
        int ex = boff[blockIdx.x] + sh[threadIdx.x] - v;
        rowptr[i] = ex;
        cursor[i] = ex;
    }
}
__global__ __launch_bounds__(256) void gin_fill(const int* __restrict__ src,
                                                const int* __restrict__ dst,
                                                int* __restrict__ cursor,
                                                int* __restrict__ csr_src, int nedges) {
    int e = blockIdx.x * 256 + threadIdx.x;
    if (e < nedges) {
        int pos = atomicAdd(&cursor[dst[e]], 1);
        csr_src[pos] = src[e];
    }
}

// ---------------- gather (bf16): hb[i] = bf16( x[i] + sum_e xb[csr_src[e]] ) ----------------
__global__ __launch_bounds__(256) void gin_gather_bf(const float* __restrict__ x,
                                                     const ushort* __restrict__ xb,
                                                     const int* __restrict__ rowptr,
                                                     const int* __restrict__ csr_src,
                                                     ushort* __restrict__ hb, int nnodes) {
    int wave = blockIdx.x * 4 + (threadIdx.x >> 6);
    int lane = threadIdx.x & 63;
    if (wave >= nnodes) return;

    int beg = rowptr[wave];
    int end = rowptr[wave + 1];

    float2 acc = *(const float2*)&x[(size_t)wave * D + lane * 2];  // self term fp32 (eps=0)
    const unsigned* xbu = (const unsigned*)xb;

    int e = beg;
    for (; e + 8 <= end; e += 8) {
        int s0 = csr_src[e],     s1 = csr_src[e + 1];
        int s2 = csr_src[e + 2], s3 = csr_src[e + 3];
        int s4 = csr_src[e + 4], s5 = csr_src[e + 5];
        int s6 = csr_src[e + 6], s7 = csr_src[e + 7];
        unsigned v0 = xbu[(size_t)s0 * 64 + lane];
        unsigned v1 = xbu[(size_t)s1 * 64 + lane];
        unsigned v2 = xbu[(size_t)s2 * 64 + lane];
        unsigned v3 = xbu[(size_t)s3 * 64 + lane];
        unsigned v4 = xbu[(size_t)s4 * 64 + lane];
        unsigned v5 = xbu[(size_t)s5 * 64 + lane];
        unsigned v6 = xbu[(size_t)s6 * 64 + lane];
        unsigned v7 = xbu[(size_t)s7 * 64 + lane];
        acc.x += ((bflo(v0) + bflo(v1)) + (bflo(v2) + bflo(v3)))
               + ((bflo(v4) + bflo(v5)) + (bflo(v6) + bflo(v7)));
        acc.y += ((bfhi(v0) + bfhi(v1)) + (bfhi(v2) + bfhi(v3)))
               + ((bfhi(v4) + bfhi(v5)) + (bfhi(v6) + bfhi(v7)));
    }
    if (e + 4 <= end) {
        int s0 = csr_src[e],     s1 = csr_src[e + 1];
        int s2 = csr_src[e + 2], s3 = csr_src[e + 3];
        unsigned v0 = xbu[(size_t)s0 * 64 + lane];
        unsigned v1 = xbu[(size_t)s1 * 64 + lane];
        unsigned v2 = xbu[(size_t)s2 * 64 + lane];
        unsigned v3 = xbu[(size_t)s3 * 64 + lane];
        acc.x += (bflo(v0) + bflo(v1)) + (bflo(v2) + bflo(v3));
        acc.y += (bfhi(v0) + bfhi(v1)) + (bfhi(v2) + bfhi(v3));
        e += 4;
    }
    for (; e < end; ++e) {
        unsigned v = xbu[(size_t)csr_src[e] * 64 + lane];
        acc.x += bflo(v);
        acc.y += bfhi(v);
    }
    unsigned o = (unsigned)f2bf(acc.x) | ((unsigned)f2bf(acc.y) << 16);
    ((unsigned*)hb)[(size_t)wave * 64 + lane] = o;
}

// ---------------- MFMA GEMM: out = hb @ Wb^T + b (bf16 in, fp32 out) ----------------
__global__ __launch_bounds__(256) void gin_gemm_mfma(const ushort* __restrict__ hb,
                                                     const ushort* __restrict__ Wb,
                                                     const float* __restrict__ bias,
                                                     float* __restrict__ out, int nrows) {
    __shared__ ushort Wl[D * LDW];   // Wl[o][k], k contiguous
    __shared__ ushort Al[64 * LDW];

    int tid = threadIdx.x;

    // stage Wb (bf16, 32 KB): 2048 uint4 chunks
    for (int i = tid; i < D * D / 8; i += 256) {
        uint4 v = ((const uint4*)Wb)[i];
        int row = i >> 4;          // 16 uint4 per 128-elem row
        int col = (i & 15) * 8;
        *(uint4*)&Wl[row * LDW + col] = v;
    }

    int base = blockIdx.x * 64;
    for (int j = tid; j < 1024; j += 256) {
        int row = j >> 4;
        int col = (j & 15) * 8;
        uint4 v = make_uint4(0, 0, 0, 0);
        if (base + row < nrows) v = *(const uint4*)&hb[(size_t)(base + row) * D + col];
        *(uint4*)&Al[row * LDW + col] = v;
    }
    __syncthreads();

    int w = tid >> 6, l = tid & 63;
    int wr = w >> 1, wc = w & 1;     // 2x2 wave grid: 32 rows x 64 cols per wave
    int lr = l & 15, hi = l >> 4;

    f32x4 acc[2][4];
#pragma unroll
    for (int m = 0; m < 2; m++)
#pragma unroll
        for (int t = 0; t < 4; t++) acc[m][t] = (f32x4)0.0f;

#pragma unroll
    for (int ks = 0; ks < 4; ks++) {
        int kof = ks * 32 + hi * 8;
        bf16x8 a0 = *(bf16x8*)&Al[(wr * 32 + lr) * LDW + kof];
        bf16x8 a1 = *(bf16x8*)&Al[(wr * 32 + 16 + lr) * LDW + kof];
#pragma unroll
        for (int t = 0; t < 4; t++) {
            bf16x8 bm = *(bf16x8*)&Wl[(wc * 64 + t * 16 + lr) * LDW + kof];
            acc[0][t] = __builtin_amdgcn_mfma_f32_16x16x32_bf16(a0, bm, acc[0][t], 0, 0, 0);
            acc[1][t] = __builtin_amdgcn_mfma_f32_16x16x32_bf16(a1, bm, acc[1][t], 0, 0, 0);
        }
    }

    // C/D layout (m89-verified): col = lane&15, row = (lane>>4)*4 + reg
#pragma unroll
    for (int m = 0; m < 2; m++) {
#pragma unroll
        for (int t = 0; t < 4; t++) {
            int col = wc * 64 + t * 16 + lr;
            float bv = bias[col];
#pragma unroll
            for (int r = 0; r < 4; r++) {
                int row = base + wr * 32 + m * 16 + hi * 4 + r;
                if (row < nrows) out[(size_t)row * D + col] = acc[m][t][r] + bv;
            }
        }
    }
}

extern "C" void kernel_launch(void* const* d_in, const int* in_sizes, int n_in,
                              void* d_out, int out_size, void* d_ws, size_t ws_size,
                              hipStream_t stream) {
    const float* x  = (const float*)d_in[0];
    const int*   ei = (const int*)d_in[1];
    const float* W  = (const float*)d_in[2];
    const float* bb = (const float*)d_in[3];
    float* out = (float*)d_out;

    int nnodes = in_sizes[0] / D;
    int nedges = in_sizes[1] / 2;
    const int* srcp = ei;
    const int* dstp = ei + nedges;

    int nb = (nnodes + 255) / 256;
    int npad = nb * 256;

    // workspace layout
    char* p = (char*)d_ws;
    int* deg     = (int*)p;  p += (size_t)npad * 4;
    int* rowptr  = (int*)p;  p += (size_t)(nnodes + 1) * 4;
    int* cursor  = (int*)p;  p += (size_t)npad * 4;
    int* bsum    = (int*)p;  p += 256 * 4;
    int* boff    = (int*)p;  p += 256 * 4;
    int* csr_src = (int*)p;  p += (size_t)nedges * 4;
    p = (char*)(((uintptr_t)p + 15) & ~(uintptr_t)15);
    ushort* xb = (ushort*)p; p += (size_t)nnodes * D * 2;
    ushort* hb = (ushort*)p; p += (size_t)nnodes * D * 2;
    ushort* Wb = (ushort*)p; p += (size_t)D * D * 2;

    int n4 = nnodes * (D / 4);
    int w4 = D * D / 4;

    // 1) prep: zero deg + cvt x->bf16 + cvt W->bf16
    gin_prep<<<2048, 256, 0, stream>>>(x, xb, n4, W, Wb, w4, deg, npad / 4);

    // 2) CSR build — one cooperative kernel (hist + scan + fill)
    bool coop_ok = (nb <= 256);
    if (coop_ok) {
        void* args[] = {(void*)&srcp, (void*)&dstp, (void*)&deg, (void*)&bsum,
                        (void*)&rowptr, (void*)&cursor, (void*)&csr_src,
                        (void*)&nnodes, (void*)&nedges};
        hipError_t err = hipLaunchCooperativeKernel((void*)gin_csr, dim3(nb), dim3(256),
                                                    args, 0, stream);
        if (err != hipSuccess) coop_ok = false;
    }
    if (!coop_ok) {
        int eb = (nedges + 255) / 256;
        gin_hist<<<eb, 256, 0, stream>>>(dstp, deg, nedges);
        gin_bsum<<<nb, 256, 0, stream>>>(deg, bsum, nnodes);
        gin_bscan<<<1, 256, 0, stream>>>(bsum, boff, rowptr, nb, nnodes);
        gin_scan<<<nb, 256, 0, stream>>>(deg, boff, rowptr, cursor, nnodes);
        gin_fill<<<eb, 256, 0, stream>>>(srcp, dstp, cursor, csr_src, nedges);
    }

    // 3) gather: one wave per node
    int gb = (nnodes + 3) / 4;
    gin_gather_bf<<<gb, 256, 0, stream>>>(x, xb, rowptr, csr_src, hb, nnodes);

    // 4) GEMM
    int gemb = (nnodes + 63) / 64;
    gin_gemm_mfma<<<gemb, 256, 0, stream>>>(hb, Wb, bb, out, nnodes);
}